// Round 4
// baseline (104.569 us; speedup 1.0000x reference)
//
#include <hip/hip_runtime.h>
#include <math.h>

#define NB   4096           // N events
#define BB   4              // batch
#define TI   512            // i per block (2 per thread)
#define TJ   128            // j per slice
#define NSL  (NB / TJ)      // 32 j-slices
#define NIT  (NB / TI)      // 8 i-tiles
#define THR  256
#define TPB  144            // valid tiles per batch: sum_{it<8} (4*it+4)

#if __has_builtin(__builtin_amdgcn_exp2f)
#define EXP2F __builtin_amdgcn_exp2f
#else
#define EXP2F exp2f
#endif

// arg = nb*(t_i - t_j) + nc*((x_i-x_j)^2 + (y_i-y_j)^2)      (log2 domain)
//     = u_i + w_j + x_i*xp_j + y_i*yp_j
// Masked j: w_j = -3e38 -> exp2 -> 0 (and tj=2.0 kills the diagonal predicate).
// 1D grid over VALID lower-triangle tiles only (TPB per batch).
// S layout: S[(b*NSL + s)*NB + i]; only valid (b,it,s) slots are written, and
// finish reads exactly the valid range s < 4*(i>>9)+4.
__global__ __launch_bounds__(THR) void hawkes_pair(
    const float* __restrict__ loc, const float* __restrict__ times,
    const int* __restrict__ mask,
    const float* __restrict__ beta_p, const float* __restrict__ sigma_p,
    float* __restrict__ S)
{
    const int b  = blockIdx.x / TPB;
    const int k  = blockIdx.x % TPB;
    // cumulative tiles before i-tile `it` is c(it)=2it^2+2it; invert via sqrt + fixup
    int it = (int)floorf((sqrtf((float)(2 * k + 1)) - 1.0f) * 0.5f);
    while (2 * (it + 1) * (it + 1) + 2 * (it + 1) <= k) ++it;
    while (2 * it * it + 2 * it > k) --it;
    const int s = k - (2 * it * it + 2 * it);

    const int tid = threadIdx.x;
    const int i0 = it * TI + tid;
    const int i1 = i0 + THR;

    const float beta  = beta_p[0];
    const float sigma = sigma_p[0];
    const float L2E = 1.4426950408889634f;
    const float nb  = -beta * L2E;
    const float nc  = -L2E / (2.0f * sigma * sigma);

    const float t0 = times[b * NB + i0];
    const float x0 = loc[(b * NB + i0) * 2 + 0];
    const float y0 = loc[(b * NB + i0) * 2 + 1];
    const float u0 = fmaf(nc, fmaf(x0, x0, y0 * y0), nb * t0);
    const float t1 = times[b * NB + i1];
    const float x1 = loc[(b * NB + i1) * 2 + 0];
    const float y1 = loc[(b * NB + i1) * 2 + 1];
    const float u1 = fmaf(nc, fmaf(x1, x1, y1 * y1), nb * t1);

    __shared__ float4 jt[TJ];
    if (tid < TJ) {
        const int j  = s * TJ + tid;
        const float tj = times[b * NB + j];
        const float xj = loc[(b * NB + j) * 2 + 0];
        const float yj = loc[(b * NB + j) * 2 + 1];
        const bool  mj = mask[b * NB + j] != 0;
        float4 v;
        v.x = mj ? fmaf(nc, fmaf(xj, xj, yj * yj), -nb * tj) : -3.0e38f;  // w_j
        v.y = mj ? (-2.0f * nc * xj) : 0.0f;                              // xp_j
        v.z = mj ? (-2.0f * nc * yj) : 0.0f;                              // yp_j
        v.w = mj ? tj : 2.0f;                                             // predicate key
        jt[tid] = v;
    }
    __syncthreads();

    float a0 = 0.0f, a1 = 0.0f;
    if (s < 4 * it) {
        // interior: every j strictly earlier (by index) than every i in tile
#pragma unroll 8
        for (int jj = 0; jj < TJ; ++jj) {
            float4 v = jt[jj];                          // LDS broadcast
            float g0 = fmaf(v.y, x0, fmaf(v.z, y0, u0 + v.x));
            float g1 = fmaf(v.y, x1, fmaf(v.z, y1, u1 + v.x));
            a0 += EXP2F(g0);
            a1 += EXP2F(g1);
        }
    } else {
        // diagonal overlap: strict dt > 0
#pragma unroll 8
        for (int jj = 0; jj < TJ; ++jj) {
            float4 v = jt[jj];
            float g0 = fmaf(v.y, x0, fmaf(v.z, y0, u0 + v.x));
            float g1 = fmaf(v.y, x1, fmaf(v.z, y1, u1 + v.x));
            float e0 = EXP2F(g0);
            float e1 = EXP2F(g1);
            a0 += (t0 > v.w) ? e0 : 0.0f;
            a1 += (t1 > v.w) ? e1 : 0.0f;
        }
    }
    float* __restrict__ Srow = S + (size_t)(b * NSL + s) * NB;
    Srow[i0] = a0;
    Srow[i1] = a1;
}

// Per-batch: sum valid slice partials, log-intensity + compensator, block-reduce.
__global__ __launch_bounds__(1024) void hawkes_finish(
    const float* __restrict__ loc, const float* __restrict__ times,
    const int* __restrict__ mask,
    const float* mu_p, const float* alpha_p, const float* beta_p, const float* sigma_p,
    const float* lo_p, const float* hi_p, const float* tend_p,
    const float* __restrict__ S, float* __restrict__ out)
{
    const int b   = blockIdx.x;
    const int tid = threadIdx.x;

    const float mu    = mu_p[0];
    const float alpha = alpha_p[0];
    const float beta  = beta_p[0];
    const float sigma = sigma_p[0];
    const float lo0 = lo_p[0], lo1 = lo_p[1];
    const float hi0 = hi_p[0], hi1 = hi_p[1];
    const float tend = tend_p[0];

    const float two_sig2 = 2.0f * sigma * sigma;
    const float an = alpha * beta / ((float)M_PI * two_sig2);   // alpha*norm, d=2
    const float inv_ss2 = 1.0f / (sigma * sqrtf(2.0f));

    float accL = 0.0f, accC = 0.0f;
    for (int i = tid; i < NB; i += 1024) {
        if (mask[b * NB + i] != 0) {
            const int smax = 4 * (i >> 9) + 4;   // valid slices for this i-tile
            float sum = 0.0f;
            for (int s = 0; s < smax; ++s)
                sum += S[(size_t)(b * NSL + s) * NB + i];
            float lam = fmaf(an, sum, mu);
            accL += logf(lam);
            float tmass = 1.0f - expf(-beta * (tend - times[b * NB + i]));
            float x = loc[(b * NB + i) * 2 + 0];
            float y = loc[(b * NB + i) * 2 + 1];
            float cx = 0.5f * (erff((hi0 - x) * inv_ss2) - erff((lo0 - x) * inv_ss2));
            float cy = 0.5f * (erff((hi1 - y) * inv_ss2) - erff((lo1 - y) * inv_ss2));
            accC += tmass * cx * cy;
        }
    }

    // 16 waves x 64 lanes
    __shared__ float redL[16], redC[16];
    for (int off = 32; off > 0; off >>= 1) {
        accL += __shfl_down(accL, off, 64);
        accC += __shfl_down(accC, off, 64);
    }
    const int wave = tid >> 6, lane = tid & 63;
    if (lane == 0) { redL[wave] = accL; redC[wave] = accC; }
    __syncthreads();
    if (tid == 0) {
        float L = 0.0f, C = 0.0f;
#pragma unroll
        for (int w = 0; w < 16; ++w) { L += redL[w]; C += redC[w]; }
        float area = (hi0 - lo0) * (hi1 - lo1);
        out[b] = L - (mu * area * tend + alpha * C);
    }
}

extern "C" void kernel_launch(void* const* d_in, const int* in_sizes, int n_in,
                              void* d_out, int out_size, void* d_ws, size_t ws_size,
                              hipStream_t stream) {
    const float* loc   = (const float*)d_in[0];
    const float* times = (const float*)d_in[1];
    const int*   mask  = (const int*)d_in[2];    // bool -> int32 per harness
    const float* mu_p    = (const float*)d_in[3];
    const float* alpha_p = (const float*)d_in[4];
    const float* beta_p  = (const float*)d_in[5];
    const float* sigma_p = (const float*)d_in[6];
    const float* lo_p    = (const float*)d_in[7];
    const float* hi_p    = (const float*)d_in[8];
    const float* tend_p  = (const float*)d_in[9];
    float* out = (float*)d_out;
    float* S   = (float*)d_ws;   // [BB][NSL][NB] slice partials (valid slots only)

    hawkes_pair<<<dim3(BB * TPB), THR, 0, stream>>>(loc, times, mask, beta_p, sigma_p, S);
    hawkes_finish<<<dim3(BB), 1024, 0, stream>>>(loc, times, mask, mu_p, alpha_p, beta_p,
                                                 sigma_p, lo_p, hi_p, tend_p, S, out);
}

// Round 5
// 91.241 us; speedup vs baseline: 1.1461x; 1.1461x over previous
//
#include <hip/hip_runtime.h>
#include <math.h>

#define NB   4096           // N events
#define BB   4              // batch
#define TI   256            // i per block (2 per thread)
#define TJ   128            // j per slice
#define NSL  (NB / TJ)      // 32 j-slices
#define THR  128            // 2 waves per block
#define TPB  272            // valid tiles per batch: sum_{it<16} (2*it+2) = 16^2+16

#if __has_builtin(__builtin_amdgcn_exp2f)
#define EXP2F __builtin_amdgcn_exp2f
#else
#define EXP2F exp2f
#endif

// ws layout: S[BB][NSL][NB] slice partials (2 MiB), then accL[BB], accC[BB], cnt[BB].
#define S_ELEMS (BB * NSL * NB)

// arg = nb*(t_i-t_j) + nc*((x_i-x_j)^2+(y_i-y_j)^2)  (log2 domain)
//     = u_i + w_j + x_i*xp_j + y_i*yp_j
// Masked j: w_j = -3e38 -> exp2 -> 0 (tj=2.0 also kills the diagonal predicate).
// 1D grid over VALID lower-triangle tiles only. Each valid S slot written once.
// Blocks with k==0 also zero the finish accumulators (finish runs after this
// dispatch completes -> safe).
__global__ __launch_bounds__(THR) void hawkes_pair(
    const float* __restrict__ loc, const float* __restrict__ times,
    const int* __restrict__ mask,
    const float* __restrict__ beta_p, const float* __restrict__ sigma_p,
    float* __restrict__ S)
{
    const int b  = blockIdx.x / TPB;
    const int k  = blockIdx.x % TPB;
    // tiles before i-tile `it`: c(it) = it^2 + it
    int it = (int)floorf((sqrtf((float)(4 * k + 1)) - 1.0f) * 0.5f);
    while ((it + 1) * (it + 1) + (it + 1) <= k) ++it;
    while (it * it + it > k) --it;
    const int s = k - (it * it + it);

    const int tid = threadIdx.x;

    if (k == 0 && tid == 0) {           // zero finish accumulators for batch b
        float* acc = S + S_ELEMS;
        acc[b] = 0.0f;                  // accL
        acc[BB + b] = 0.0f;             // accC
        ((int*)(acc + 2 * BB))[b] = 0;  // cnt
    }

    const int i0 = it * TI + tid;
    const int i1 = i0 + THR;

    const float beta  = beta_p[0];
    const float sigma = sigma_p[0];
    const float L2E = 1.4426950408889634f;
    const float nb  = -beta * L2E;
    const float nc  = -L2E / (2.0f * sigma * sigma);

    const float t0 = times[b * NB + i0];
    const float x0 = loc[(b * NB + i0) * 2 + 0];
    const float y0 = loc[(b * NB + i0) * 2 + 1];
    const float u0 = fmaf(nc, fmaf(x0, x0, y0 * y0), nb * t0);
    const float t1 = times[b * NB + i1];
    const float x1 = loc[(b * NB + i1) * 2 + 0];
    const float y1 = loc[(b * NB + i1) * 2 + 1];
    const float u1 = fmaf(nc, fmaf(x1, x1, y1 * y1), nb * t1);

    __shared__ float4 jt[TJ];
    {
        const int j  = s * TJ + tid;
        const float tj = times[b * NB + j];
        const float xj = loc[(b * NB + j) * 2 + 0];
        const float yj = loc[(b * NB + j) * 2 + 1];
        const bool  mj = mask[b * NB + j] != 0;
        float4 v;
        v.x = mj ? fmaf(nc, fmaf(xj, xj, yj * yj), -nb * tj) : -3.0e38f;  // w_j
        v.y = mj ? (-2.0f * nc * xj) : 0.0f;                              // xp_j
        v.z = mj ? (-2.0f * nc * yj) : 0.0f;                              // yp_j
        v.w = mj ? tj : 2.0f;                                             // predicate key
        jt[tid] = v;
    }
    __syncthreads();

    float a0 = 0.0f, a1 = 0.0f;
    if (s < 2 * it) {
        // interior: every j strictly earlier (by index) than every i in tile
#pragma unroll 8
        for (int jj = 0; jj < TJ; ++jj) {
            float4 v = jt[jj];                          // LDS broadcast
            float g0 = fmaf(v.y, x0, fmaf(v.z, y0, u0 + v.x));
            float g1 = fmaf(v.y, x1, fmaf(v.z, y1, u1 + v.x));
            a0 += EXP2F(g0);
            a1 += EXP2F(g1);
        }
    } else {
        // diagonal tiles: strict dt > 0
#pragma unroll 8
        for (int jj = 0; jj < TJ; ++jj) {
            float4 v = jt[jj];
            float g0 = fmaf(v.y, x0, fmaf(v.z, y0, u0 + v.x));
            float g1 = fmaf(v.y, x1, fmaf(v.z, y1, u1 + v.x));
            float e0 = EXP2F(g0);
            float e1 = EXP2F(g1);
            a0 += (t0 > v.w) ? e0 : 0.0f;
            a1 += (t1 > v.w) ? e1 : 0.0f;
        }
    }
    float* __restrict__ Srow = S + (size_t)(b * NSL + s) * NB;
    Srow[i0] = a0;
    Srow[i1] = a1;
}

// 16 blocks per batch, 256 i's each. Partial L/C -> device atomics; last
// arriving block per batch finalizes out[b].
__global__ __launch_bounds__(256) void hawkes_finish(
    const float* __restrict__ loc, const float* __restrict__ times,
    const int* __restrict__ mask,
    const float* mu_p, const float* alpha_p, const float* beta_p, const float* sigma_p,
    const float* lo_p, const float* hi_p, const float* tend_p,
    float* __restrict__ S, float* __restrict__ out)
{
    const int b   = blockIdx.x >> 4;          // 16 blocks per batch
    const int r   = blockIdx.x & 15;
    const int tid = threadIdx.x;
    const int i   = r * 256 + tid;            // one event per thread

    const float mu    = mu_p[0];
    const float alpha = alpha_p[0];
    const float beta  = beta_p[0];
    const float sigma = sigma_p[0];
    const float lo0 = lo_p[0], lo1 = lo_p[1];
    const float hi0 = hi_p[0], hi1 = hi_p[1];
    const float tend = tend_p[0];

    const float two_sig2 = 2.0f * sigma * sigma;
    const float an = alpha * beta / ((float)M_PI * two_sig2);   // alpha*norm, d=2
    const float inv_ss2 = 1.0f / (sigma * sqrtf(2.0f));

    float accL = 0.0f, accC = 0.0f;
    if (mask[b * NB + i] != 0) {
        const int smax = 2 * (i >> 8) + 2;    // valid slices for this i-tile
        float sum = 0.0f;
        for (int s = 0; s < smax; ++s)
            sum += S[(size_t)(b * NSL + s) * NB + i];
        float lam = fmaf(an, sum, mu);
        accL = logf(lam);
        float tmass = 1.0f - expf(-beta * (tend - times[b * NB + i]));
        float x = loc[(b * NB + i) * 2 + 0];
        float y = loc[(b * NB + i) * 2 + 1];
        float cx = 0.5f * (erff((hi0 - x) * inv_ss2) - erff((lo0 - x) * inv_ss2));
        float cy = 0.5f * (erff((hi1 - y) * inv_ss2) - erff((lo1 - y) * inv_ss2));
        accC = tmass * cx * cy;
    }

    // block reduction: 4 waves x 64 lanes
    __shared__ float redL[4], redC[4];
    for (int off = 32; off > 0; off >>= 1) {
        accL += __shfl_down(accL, off, 64);
        accC += __shfl_down(accC, off, 64);
    }
    const int wave = tid >> 6, lane = tid & 63;
    if (lane == 0) { redL[wave] = accL; redC[wave] = accC; }
    __syncthreads();

    if (tid == 0) {
        float L = redL[0] + redL[1] + redL[2] + redL[3];
        float C = redC[0] + redC[1] + redC[2] + redC[3];
        float* accLg = S + S_ELEMS;
        float* accCg = accLg + BB;
        int*   cnt   = (int*)(accLg + 2 * BB);
        atomicAdd(&accLg[b], L);
        atomicAdd(&accCg[b], C);
        __threadfence();
        int old = atomicAdd(&cnt[b], 1);
        if (old == 15) {                       // last block for this batch
            __threadfence();
            float Lt = atomicAdd(&accLg[b], 0.0f);
            float Ct = atomicAdd(&accCg[b], 0.0f);
            float area = (hi0 - lo0) * (hi1 - lo1);
            out[b] = Lt - (mu * area * tend + alpha * Ct);
        }
    }
}

extern "C" void kernel_launch(void* const* d_in, const int* in_sizes, int n_in,
                              void* d_out, int out_size, void* d_ws, size_t ws_size,
                              hipStream_t stream) {
    const float* loc   = (const float*)d_in[0];
    const float* times = (const float*)d_in[1];
    const int*   mask  = (const int*)d_in[2];    // bool -> int32 per harness
    const float* mu_p    = (const float*)d_in[3];
    const float* alpha_p = (const float*)d_in[4];
    const float* beta_p  = (const float*)d_in[5];
    const float* sigma_p = (const float*)d_in[6];
    const float* lo_p    = (const float*)d_in[7];
    const float* hi_p    = (const float*)d_in[8];
    const float* tend_p  = (const float*)d_in[9];
    float* out = (float*)d_out;
    float* S   = (float*)d_ws;   // [BB][NSL][NB] partials + accumulators

    hawkes_pair<<<dim3(BB * TPB), THR, 0, stream>>>(loc, times, mask, beta_p, sigma_p, S);
    hawkes_finish<<<dim3(BB * 16), 256, 0, stream>>>(loc, times, mask, mu_p, alpha_p, beta_p,
                                                     sigma_p, lo_p, hi_p, tend_p, S, out);
}